// Round 16
// baseline (575.347 us; speedup 1.0000x reference)
//
#include <hip/hip_runtime.h>

// MoE MLP (B=2,T=2048,H=1024,E=8,F=4096,K=2), fp32 in/out.
// route -> one-time weight transpose+bf16 convert (tconv) -> grouped GEMMs:
// 128x128 tile, 4 waves, BK=32, BOTH operands global_load_lds into a
// kc-major double-buffered 32KB LDS (conflict-free by construction),
// stage-ahead overlap + one barrier/step, 5 blocks/CU -> weighted combine.
// G2 = split-K2 with bf16 partials (summed with b2 in combine).
// r16 fix vs r15: staging source k-offset includes the wave's kc0 slot
// (waves 2/3 were re-loading k-elems 0..15 into kc slots 2/3).

typedef unsigned short ushort_t;
typedef __attribute__((ext_vector_type(4))) unsigned int u32x4;
typedef __attribute__((ext_vector_type(4))) unsigned short u16x4;
typedef __attribute__((ext_vector_type(4))) float f32x4;
typedef __attribute__((ext_vector_type(8))) __bf16 bf16x8;

#define NTOK 4096   // B*T
#define HD   1024
#define FD   4096
#define NE   8
#define NKTOT 8192  // NTOK * TOP_K

__device__ __forceinline__ ushort_t f2bf(float f) {
  unsigned u = __builtin_bit_cast(unsigned, f);
  u += 0x7fffu + ((u >> 16) & 1u);   // RNE
  return (ushort_t)(u >> 16);
}
__device__ __forceinline__ float bf2f(ushort_t u) {
  unsigned v = ((unsigned)u) << 16;
  return __builtin_bit_cast(float, v);
}
__device__ __forceinline__ bf16x8 frag_ld(const void* p) {
  u32x4 v = *reinterpret_cast<const u32x4*>(p);
  return __builtin_bit_cast(bf16x8, v);
}

#define GLOAD16(g, l) __builtin_amdgcn_global_load_lds(                         \
    (const __attribute__((address_space(1))) unsigned int*)(g),                 \
    (__attribute__((address_space(3))) unsigned int*)(l), 16, 0, 0)

#define WAITVM0() asm volatile("s_waitcnt vmcnt(0)" ::: "memory")
#define BARRIER() do { asm volatile("s_waitcnt lgkmcnt(0)" ::: "memory");       \
                       __builtin_amdgcn_s_barrier(); } while (0)

// ---------------------------------------------------------------- init
__global__ void init_k(int* counts) {
  if (threadIdx.x < NE) counts[threadIdx.x] = 0;
}

// --------------------------- transpose+convert: src[z][R][C] -> dst[z][C][R]
// (r2/r14-proven vectorized version: f32x4 in, u16x4 out)
__global__ void tconv_k(const float* __restrict__ src, ushort_t* __restrict__ dst,
                        int R, int C) {
  __shared__ float tile[64][65];
  const size_t zb = (size_t)blockIdx.z * R * C;
  const int r0 = blockIdx.y * 64, c0 = blockIdx.x * 64;
  const int tid = threadIdx.x;
  const int rl = tid >> 4, c4 = (tid & 15) * 4;
#pragma unroll
  for (int i = 0; i < 4; ++i) {
    const int r = rl + i * 16;
    const f32x4 v = *reinterpret_cast<const f32x4*>(src + zb + (size_t)(r0 + r) * C + c0 + c4);
    tile[r][c4 + 0] = v.x; tile[r][c4 + 1] = v.y;
    tile[r][c4 + 2] = v.z; tile[r][c4 + 3] = v.w;
  }
  __syncthreads();
  const int rr0 = (tid & 15) * 4, ccl = tid >> 4;
#pragma unroll
  for (int i = 0; i < 4; ++i) {
    const int cc = ccl + i * 16;
    u16x4 o;
    o.x = f2bf(tile[rr0 + 0][cc]); o.y = f2bf(tile[rr0 + 1][cc]);
    o.z = f2bf(tile[rr0 + 2][cc]); o.w = f2bf(tile[rr0 + 3][cc]);
    *reinterpret_cast<u16x4*>(dst + zb + (size_t)(c0 + cc) * R + r0 + rr0) = o;
  }
}

// ------------------------------------------- router (+ fused x->bf16 conv)
__global__ void router_k(const float* __restrict__ x, const float* __restrict__ rw,
                         ushort_t* __restrict__ Xbf,
                         float* __restrict__ tokP, int* __restrict__ counts,
                         int* __restrict__ tk_e, int* __restrict__ tk_s,
                         float* __restrict__ tk_w) {
  const int w = threadIdx.x >> 6, l = threadIdx.x & 63;
  const int t = blockIdx.x * 4 + w;
  const float* xr = x + (size_t)t * HD;
  ushort_t* xo = Xbf + (size_t)t * HD;
  float acc[NE];
#pragma unroll
  for (int e = 0; e < NE; ++e) acc[e] = 0.f;
  for (int it = 0; it < HD / 64; ++it) {
    const int h = l + it * 64;
    const float xv = xr[h];
    xo[h] = f2bf(xv);
#pragma unroll
    for (int e = 0; e < NE; ++e) acc[e] = fmaf(xv, rw[e * HD + h], acc[e]);
  }
#pragma unroll
  for (int e = 0; e < NE; ++e) {
#pragma unroll
    for (int s = 32; s > 0; s >>= 1) acc[e] += __shfl_xor(acc[e], s, 64);
  }
  float m = acc[0];
#pragma unroll
  for (int e = 1; e < NE; ++e) m = fmaxf(m, acc[e]);
  float ssum = 0.f;
  float p[NE];
#pragma unroll
  for (int e = 0; e < NE; ++e) { p[e] = expf(acc[e] - m); ssum += p[e]; }
  const float inv = 1.f / ssum;
  if (l < NE) tokP[(size_t)t * NE + l] = p[l] * inv;

  if (l == 0) {
    int i0 = 0; float v0 = acc[0];
#pragma unroll
    for (int e = 1; e < NE; ++e) if (acc[e] > v0) { v0 = acc[e]; i0 = e; }
    int i1 = -1; float v1 = -3.4e38f;
#pragma unroll
    for (int e = 0; e < NE; ++e) if (e != i0 && acc[e] > v1) { v1 = acc[e]; i1 = e; }
    const float w0 = 1.f / (1.f + expf(v1 - v0));
    const int s0 = atomicAdd(&counts[i0], 1);
    const int s1 = atomicAdd(&counts[i1], 1);
    tk_e[2 * t] = i0;     tk_s[2 * t] = s0;     tk_w[2 * t] = w0;
    tk_e[2 * t + 1] = i1; tk_s[2 * t + 1] = s1; tk_w[2 * t + 1] = 1.f - w0;
  }
}

// ------------------------------------------- offsets + aux loss + tail out
__global__ void finalize_k(const float* __restrict__ tokP, const int* __restrict__ counts,
                           int* __restrict__ offsets, float* __restrict__ out_tail) {
  __shared__ float red[16][8];
  const int tid = threadIdx.x;  // 1024
  f32x4 a0 = {0.f, 0.f, 0.f, 0.f}, a1 = {0.f, 0.f, 0.f, 0.f};
#pragma unroll
  for (int k = 0; k < 4; ++k) {
    const float* p = tokP + ((size_t)tid * 4 + k) * 8;
    a0 += *reinterpret_cast<const f32x4*>(p);
    a1 += *reinterpret_cast<const f32x4*>(p + 4);
  }
#pragma unroll
  for (int s = 1; s < 64; s <<= 1) {
#pragma unroll
    for (int c = 0; c < 4; ++c) {
      a0[c] += __shfl_xor(a0[c], s, 64);
      a1[c] += __shfl_xor(a1[c], s, 64);
    }
  }
  if ((tid & 63) == 0) {
    const int wv = tid >> 6;
#pragma unroll
    for (int c = 0; c < 4; ++c) { red[wv][c] = a0[c]; red[wv][4 + c] = a1[c]; }
  }
  __syncthreads();
  if (tid == 0) {
    float P[8];
    for (int c = 0; c < 8; ++c) {
      float s = 0.f;
      for (int q = 0; q < 16; ++q) s += red[q][c];
      P[c] = s * (1.f / NTOK);
    }
    int off = 0; float aux = 0.f;
    for (int q = 0; q < NE; ++q) { offsets[q] = off; off += counts[q]; }
    for (int q = 0; q < NE; ++q) aux += ((float)counts[q] / (float)NKTOT) * P[q];
    out_tail[0] = (float)NE * aux;
    out_tail[1] = 0.f;
  }
}

// ---------------------------------------------------------------- slots
__global__ void build_slots_k(const int* __restrict__ tk_e, const int* __restrict__ tk_s,
                              const int* __restrict__ offsets, int* __restrict__ slot_token) {
  const int i = blockIdx.x * 256 + threadIdx.x;  // < NKTOT
  const int e = tk_e[i];
  slot_token[offsets[e] + tk_s[i]] = i >> 1;
}

// ------ grouped GEMM: 128x128, BK=32, kc-major dbuf LDS, 5 blocks/CU -------
// 256 thr = 4 waves (2M x 2N, 64x64 each, acc 4x4).  LDS 32KB total:
//   As[2][kc 4][r 128][8e] bf16 (2x8KB) + Bs same at +8192 ushorts.
//   kc-major: gload_lds dest = uniform base + lane*16B (linear ✓); frag
//   read = 16 lanes x 16B contiguous per kc region -> conflict-free by
//   construction, NO swizzle anywhere.
// Staging: wave w covers rhalf = w&1, kc = {kc0, kc0+1}, kc0 = 2*(w>>1);
// lane row = rhalf*64 + l; GLOBAL source k-offset = t*64 + kc*16 BYTES
// (r16 fix: kc0 term was missing).  Per step t: stage(t+1 -> buf^1);
// compute(t on buf) [8 ds_read_b128 + 16 MFMA]; vmcnt(0); barrier.
// 5 blocks/CU (launch_bounds 256,5; LDS 160/32=5) cover the residue.
// G1: mid = gelu(X@w1+b1) bf16, NSTEP=32.  G2: bf16 k-slice partials
// (ks=2, K-window 2048, NSTEP=64).
template <bool IS_G1>
__global__ __launch_bounds__(256, 5) void moe_gemm(
    const ushort_t* __restrict__ A, const ushort_t* __restrict__ BT,
    const float* __restrict__ bias,
    const int* __restrict__ counts, const int* __restrict__ offsets,
    const int* __restrict__ slot_token,
    ushort_t* __restrict__ midout, ushort_t* __restrict__ ybuf) {
  constexpr int KDF = IS_G1 ? HD : FD;   // A / BT row stride (elems)
  constexpr int ND  = IS_G1 ? FD : HD;   // BT rows per expert
  constexpr int NSTEP = IS_G1 ? 32 : 64;
  const int id = blockIdx.x;
  const int e = id & 7;                  // XCD pin
  const int q = id >> 3;
  const int ty = q % 10;                 // ty-inner: same-panel blocks cluster
  const int r = q / 10;
  const int np = IS_G1 ? r : (r >> 1);
  const int ks = IS_G1 ? 0 : (r & 1);
  const int n0 = np * 128;
  const int KB = ks * 2048;              // k window base (elems)
  const int cnt = counts[e];
  if (ty * 128 >= cnt) return;
  const int off = offsets[e];
  const int pos0 = off + ty * 128;
  const int rr = cnt - ty * 128;
  const int rows_rem = rr < 128 ? rr : 128;

  // ushort idx: As[buf] at buf*4096; Bs[buf] at 8192 + buf*4096.  32 KB.
  __shared__ __align__(16) ushort_t lds[16384];

  const int tid = threadIdx.x;
  const int w = tid >> 6, l = tid & 63;
  const int wr = w >> 1, wc = w & 1;     // 2 (M) x 2 (N) waves, 64x64 each

  // ---- staging: wave w covers rhalf = w&1, kc = {kc0, kc0+1};
  // lane row = rhalf*64 + l  (one row pointer per lane per operand).
  const int rhalf = w & 1;
  const int kc0 = (w >> 1) * 2;
  const int srow = rhalf * 64 + l;
  int pos = pos0 + srow; if (pos > NKTOT - 1) pos = NKTOT - 1;
  const size_t arG = IS_G1 ? (size_t)slot_token[pos] : (size_t)pos;
  // r16 FIX: include the wave's kc0 slot in the global source offset.
  const char* ap = (const char*)A + (arG * KDF + KB) * 2 + kc0 * 16;
  const char* bp = (const char*)BT + (((size_t)e * ND + n0 + srow) * KDF + KB) * 2 + kc0 * 16;
  ushort_t* dA0 = &lds[kc0 * 1024 + rhalf * 512];          // + buf*4096
  ushort_t* dB0 = &lds[8192 + kc0 * 1024 + rhalf * 512];

  f32x4 acc[4][4] = {};

  auto stage = [&](int t, int buf) {
    const int tb = t * 64;               // byte offset into k (32 elems)
    GLOAD16(ap + tb,      dA0 + buf * 4096);
    GLOAD16(ap + tb + 16, dA0 + buf * 4096 + 1024);
    GLOAD16(bp + tb,      dB0 + buf * 4096);
    GLOAD16(bp + tb + 16, dB0 + buf * 4096 + 1024);
  };
  auto compute = [&](int buf) {
    const ushort_t* Ab = &lds[buf * 4096];
    const ushort_t* Bb = &lds[8192 + buf * 4096];
    const int kc = l >> 4;
    const int arow = wr * 64 + (l & 15);
    const int brow = wc * 64 + (l & 15);
    bf16x8 afr[4];
#pragma unroll
    for (int mm = 0; mm < 4; ++mm)
      afr[mm] = frag_ld(&Ab[kc * 1024 + (arow + mm * 16) * 8]);
    __builtin_amdgcn_s_setprio(1);
#pragma unroll
    for (int nn = 0; nn < 4; ++nn) {
      const bf16x8 bfr = frag_ld(&Bb[kc * 1024 + (brow + nn * 16) * 8]);
#pragma unroll
      for (int mm = 0; mm < 4; ++mm)
        acc[mm][nn] = __builtin_amdgcn_mfma_f32_16x16x32_bf16(
            afr[mm], bfr, acc[mm][nn], 0, 0, 0);
    }
    __builtin_amdgcn_s_setprio(0);
  };

  // ---- prologue: tile 0 -> buf 0.
  stage(0, 0);
  WAITVM0();
  BARRIER();

  // ---- main loop: stage-ahead, one barrier per step.
  for (int t = 0; t < NSTEP; ++t) {
    if (t + 1 < NSTEP) stage(t + 1, (t + 1) & 1);
    __builtin_amdgcn_sched_barrier(0);   // keep stage issues ahead of compute
    compute(t & 1);
    WAITVM0();                           // this wave's stage(t+1) landed
    BARRIER();                           // everyone's landed; buf^1 ready
  }

  // ---- epilogue: acc -> bf16 via LDS repack, coalesced 16B row stores.
  // C/D: col = l&15, row = 4*(l>>4)+j within each 16x16 frag. (r12/r14-proven)
  {
    const int lr4 = (l >> 4) * 4, lc = l & 15;
#pragma unroll
    for (int nn = 0; nn < 4; ++nn) {
      const int col = wc * 64 + nn * 16 + lc;
      const float bv = IS_G1 ? bias[(size_t)e * FD + n0 + col] : 0.f;
#pragma unroll
      for (int mm = 0; mm < 4; ++mm) {
        const int rb = wr * 64 + mm * 16 + lr4;
#pragma unroll
        for (int j = 0; j < 4; ++j) {
          float v = acc[mm][nn][j] + bv;
          if (IS_G1) v = 0.5f * v * (1.0f + erff(v * 0.70710678118654752f));
          lds[(rb + j) * 128 + col] = f2bf(v);
        }
      }
    }
    BARRIER();
#pragma unroll
    for (int p = 0; p < 8; ++p) {
      const int idx = p * 2048 + tid * 8;
      const int row = idx >> 7;
      const int col = idx & 127;
      if (row < rows_rem) {
        const u32x4 v = *reinterpret_cast<const u32x4*>(&lds[idx]);
        if (IS_G1)
          *reinterpret_cast<u32x4*>(&midout[(size_t)(pos0 + row) * FD + n0 + col]) = v;
        else
          *reinterpret_cast<u32x4*>(
              &ybuf[((size_t)ks * NKTOT + pos0 + row) * HD + n0 + col]) = v;
      }
    }
  }
}

// ---------------------------------------------------------------- combine
__global__ void combine_k(const ushort_t* __restrict__ ybuf, const int* __restrict__ tk_e,
                          const int* __restrict__ tk_s, const float* __restrict__ tk_w,
                          const int* __restrict__ offsets, const float* __restrict__ b2,
                          float* __restrict__ out) {
  const int t = blockIdx.x;
  const int e0 = tk_e[2 * t], e1 = tk_e[2 * t + 1];
  const size_t p0 = (size_t)offsets[e0] + tk_s[2 * t];
  const size_t p1 = (size_t)offsets[e1] + tk_s[2 * t + 1];
  const float w0 = tk_w[2 * t], w1v = tk_w[2 * t + 1];
  const int h = threadIdx.x * 4;
  f32x4 s0 = *reinterpret_cast<const f32x4*>(b2 + (size_t)e0 * HD + h);
  f32x4 s1 = *reinterpret_cast<const f32x4*>(b2 + (size_t)e1 * HD + h);
#pragma unroll
  for (int ks = 0; ks < 2; ++ks) {
    const u16x4 a = *reinterpret_cast<const u16x4*>(
        &ybuf[((size_t)ks * NKTOT + p0) * HD + h]);
    const u16x4 b = *reinterpret_cast<const u16x4*>(
        &ybuf[((size_t)ks * NKTOT + p1) * HD + h]);
    s0.x += bf2f(a.x); s0.y += bf2f(a.y); s0.z += bf2f(a.z); s0.w += bf2f(a.w);
    s1.x += bf2f(b.x); s1.y += bf2f(b.y); s1.z += bf2f(b.z); s1.w += bf2f(b.w);
  }
  f32x4 o = s0 * w0 + s1 * w1v;
  *reinterpret_cast<f32x4*>(out + (size_t)t * HD + h) = o;
}

// ---------------------------------------------------------------- launch
extern "C" void kernel_launch(void* const* d_in, const int* in_sizes, int n_in,
                              void* d_out, int out_size, void* d_ws, size_t ws_size,
                              hipStream_t stream) {
  const float* x  = (const float*)d_in[0];
  const float* rw = (const float*)d_in[1];
  const float* w1 = (const float*)d_in[2];
  const float* b1 = (const float*)d_in[3];
  const float* w2 = (const float*)d_in[4];
  const float* b2 = (const float*)d_in[5];
  float* out = (float*)d_out;

  char* ws = (char*)d_ws;
  ushort_t* Xbf  = (ushort_t*)(ws + 0);            //   8,388,608
  ushort_t* W1T  = (ushort_t*)(ws + 8388608);      //  67,108,864  [E][F][H] bf16
  ushort_t* W2T  = (ushort_t*)(ws + 75497472);     //  67,108,864  [E][H][F] bf16
  ushort_t* midb = (ushort_t*)(ws + 142606336);    //  67,108,864  [NKTOT][F] bf16
  ushort_t* ybuf = (ushort_t*)(ws + 8388608);      //  33,554,432  [2][NKTOT][H], aliases W1T (dead after G1)
  char* sm = ws + 209715200;
  int*   counts  = (int*)(sm);
  int*   offsets = (int*)(sm + 64);
  float* tokP    = (float*)(sm + 128);             // [NTOK][NE]
  int*   tk_e    = (int*)(sm + 128 + 131072);
  int*   tk_s    = (int*)(sm + 128 + 131072 + 32768);
  float* tk_w    = (float*)(sm + 128 + 131072 + 65536);
  int*   slot_token = (int*)(sm + 128 + 131072 + 98304);

  init_k<<<1, 64, 0, stream>>>(counts);
  tconv_k<<<dim3(64, 16, 8), 256, 0, stream>>>(w1, W1T, HD, FD);  // [H][F]->[F][H]
  tconv_k<<<dim3(16, 64, 8), 256, 0, stream>>>(w2, W2T, FD, HD);  // [F][H]->[H][F]
  router_k<<<1024, 256, 0, stream>>>(x, rw, Xbf, tokP, counts, tk_e, tk_s, tk_w);
  finalize_k<<<1, 1024, 0, stream>>>(tokP, counts, offsets, out + (size_t)NTOK * HD);
  build_slots_k<<<32, 256, 0, stream>>>(tk_e, tk_s, offsets, slot_token);
  // G1 grid: e(8) x [np(32) x ty(10)] = 2560 blocks
  moe_gemm<true><<<2560, 256, 0, stream>>>(
      Xbf, W1T, b1, counts, offsets, slot_token, midb, (ushort_t*)nullptr);
  // G2 grid: e(8) x [np(8) x ks(2) x ty(10)] = 1280 blocks
  moe_gemm<false><<<1280, 256, 0, stream>>>(
      midb, W2T, b2, counts, offsets, slot_token, (ushort_t*)nullptr, ybuf);
  combine_k<<<4096, 256, 0, stream>>>(ybuf, tk_e, tk_s, tk_w, offsets, b2, out);
}